// Round 9
// baseline (1089.695 us; speedup 1.0000x reference)
//
#include <hip/hip_runtime.h>
#include <stdint.h>

typedef unsigned int u32;
typedef unsigned short u16;
typedef __attribute__((ext_vector_type(8))) short short8;
typedef __attribute__((ext_vector_type(4))) float f32x4;

#define N_NODESC 30522
#define HIDC 768
#define NEC 488352
#define TOKM 2048
#define LLAY 12
#define NCLS 101
#define M_PAD 30720     // 120*256
#define ZNC (LLAY*HIDC) // 9216
#define OUT_SET (LLAY*4*513*HIDC)
#define PN_KCHUNK 512
#define NBLK 120
#define NN1 (N_NODESC+1)
#define G4_LDS 65536
#define ZC_LDS 65536

// ---------- helpers ----------
__device__ __forceinline__ float bl(u32 u){ return __uint_as_float(u<<16); }
__device__ __forceinline__ float bh(u32 u){ return __uint_as_float(u & 0xffff0000u); }
__device__ __forceinline__ u32 f2b1(float f){ u32 x=__float_as_uint(f); return (x + 0x7fffu + ((x>>16)&1u))>>16; }
__device__ __forceinline__ u32 pack2(float a, float b){ return f2b1(a) | (f2b1(b)<<16); }

__device__ __forceinline__ void mfma16(f32x4& d, short8 a, short8 b){
  asm volatile("v_mfma_f32_16x16x32_bf16 %0, %1, %2, %0" : "+v"(d) : "v"(a), "v"(b));
}
__device__ __forceinline__ void async16(const void* g, void* l){
  __builtin_amdgcn_global_load_lds((const __attribute__((address_space(1))) u32*)g,
                                   (__attribute__((address_space(3))) u32*)l, 16, 0, 0);
}
// bit-identical decode of a float2 {src_as_float_bits, weight} loaded as one double
__device__ __forceinline__ void em_dec(double d, int& s, float& w){
  unsigned long long b = __double_as_longlong(d);
  s = (int)(u32)b;
  w = __uint_as_float((u32)(b>>32));
}

// ---------- mask normalize ----------
__global__ void k_invmask(const void* __restrict__ mask, float* __restrict__ invm){
  __shared__ int s_byte, s_flt;
  int t = threadIdx.x;
  const unsigned char* mb = (const unsigned char*)mask;
  const u32* mw = (const u32*)mask;
  int lb=0, lf=0;
  for(int i=t;i<2048;i+=256) if((i&3)!=0 && mb[i]!=0) lb=1;
  for(int i=t;i<512;i+=256) if(mw[i]==0x3F800000u) lf=1;
  if(t==0){ s_byte=0; s_flt=0; }
  __syncthreads();
  if(lb) s_byte=1;
  if(lf) s_flt=1;
  __syncthreads();
  int mode = s_flt ? 2 : (s_byte ? 1 : 0);
  for(int p=t;p<2048;p+=256){
    int mv = (mode==1) ? (int)mb[p] : (int)(mw[p]!=0u);
    invm[p] = mv ? 0.f : 1.f;
  }
}

// token->node marking + node->token inverted chain (TMAP pre-memset -1, NEED1 pre-memset 0)
__global__ void k_needed(const int* __restrict__ ids, u32* __restrict__ needed,
                         u32* __restrict__ need1,
                         int* __restrict__ tmap, int* __restrict__ nxt){
  int p = blockIdx.x*256 + threadIdx.x;
  if(p < TOKM){
    int id = ids[p];
    if(id < N_NODESC){
      needed[id] = 1u;
      need1[id] = 1u;
      need1[N_NODESC + id] = 1u;
      int old = atomicExch(&tmap[id], p);
      nxt[p] = old;
    }
  }
}

__global__ void k_need_expand(const int* __restrict__ coei, const int* __restrict__ reei,
                              const u32* __restrict__ needed, u32* __restrict__ need1){
  int g = blockIdx.y;
  const int* ei = g ? reei : coei;
  int e = blockIdx.x*256 + threadIdx.x;
  if(e < NEC){
    int d = ei[NEC+e];
    if(needed[d]) need1[(size_t)g*N_NODESC + ei[e]] = 1u;
  }
}

// ---------- converts (merged: pnW + zw + zwp + pn_graph) ----------
__global__ void k_convAll(const float* __restrict__ pnW, const float* __restrict__ zw,
                          const float* __restrict__ zwp, const float* __restrict__ png,
                          u16* __restrict__ pnwb, u16* __restrict__ zwall,
                          u16* __restrict__ pnb){
  const int NP = HIDC*HIDC/2;
  const int NZ = ZNC*HIDC/2;
  const int NB = 128*(M_PAD/2);
  int i = blockIdx.x*256 + threadIdx.x;
  if(i < NP){
    ((u32*)pnwb)[i] = pack2(pnW[2*i], pnW[2*i+1]);
  } else if(i < NP + NZ){
    int j = i - NP;
    ((u32*)zwall)[j] = pack2(zw[2*j], zw[2*j+1]);
  } else if(i < NP + 2*NZ){
    int j = i - NP - NZ;
    ((u32*)zwall)[NZ + j] = pack2(zwp[2*j], zwp[2*j+1]);
  } else if(i < NP + 2*NZ + NB){
    int j = i - NP - 2*NZ;
    int row = j/(M_PAD/2); int k2 = (j - row*(M_PAD/2))*2;
    float lo=0.f, hi=0.f;
    if(row < NCLS){
      const float* s = png + (size_t)row*N_NODESC;
      if(k2 < N_NODESC) lo = s[k2];
      if(k2+1 < N_NODESC) hi = s[k2+1];
    }
    ((u32*)pnb)[j] = pack2(lo, hi);
  }
}
__global__ void k_conv_pad(const float* __restrict__ src, u16* __restrict__ dst, int srcRows, int padRows){
  int i = blockIdx.x*256 + threadIdx.x;
  if(i >= padRows*384) return;
  int row = i/384; int c2 = (i - row*384)*2;
  float lo=0.f, hi=0.f;
  if(row < srcRows){ const float* s = src + (size_t)row*HIDC + c2; lo=s[0]; hi=s[1]; }
  ((u32*)dst)[i] = pack2(lo, hi);
}
__global__ void k_transposeW2(const float* __restrict__ coW, const float* __restrict__ reW,
                              u16* __restrict__ Wt2){
  int g = blockIdx.y;
  int i = blockIdx.x*256 + threadIdx.x;
  if(i >= 3*HIDC*384) return;
  const float* W = g ? reW : coW;
  int mat = i/(HIDC*384); int rem = i - mat*HIDC*384;
  int n = rem/384; int kd = rem - n*384;
  const float* Wm = W + (size_t)mat*HIDC*HIDC;
  float lo = Wm[(size_t)(2*kd)*HIDC + n];
  float hi = Wm[(size_t)(2*kd+1)*HIDC + n];
  ((u32*)Wt2)[(size_t)g*3*HIDC*384 + (size_t)mat*HIDC*384 + (size_t)n*384 + kd] = pack2(lo, hi);
}

// ---------- batched graph prep ----------
__global__ void k_degcnt2(const int* __restrict__ coei, const int* __restrict__ reei,
                          const float* __restrict__ coew, const float* __restrict__ reew,
                          float* __restrict__ deg2, int* __restrict__ cnt2){
  int g = blockIdx.y;
  const int* ei = g ? reei : coei;
  const float* ew = g ? reew : coew;
  int e = blockIdx.x*256 + threadIdx.x;
  if(e < NEC){ int d = ei[NEC+e]; atomicAdd(&deg2[(size_t)g*N_NODESC + d], ew[e]); atomicAdd(&cnt2[(size_t)g*N_NODESC + d], 1); }
}
// scan1 with fused dinv computation
__global__ void k_scan1(const int* __restrict__ cnt2, int* __restrict__ part2,
                        const float* __restrict__ deg2,
                        float* __restrict__ dinvA, float* __restrict__ dinvB){
  __shared__ int wt[4];
  int g = blockIdx.y, b = blockIdx.x, t = threadIdx.x;
  int lane = t & 63, w = t >> 6;
  int i = b*256 + t;
  if(i < N_NODESC){
    float d = deg2[(size_t)g*N_NODESC + i] + 1.f;
    dinvA[(size_t)g*N_NODESC + i] = rsqrtf(d);
    dinvB[(size_t)g*N_NODESC + i] = 1.f/d;
  }
  int v = (i < N_NODESC) ? cnt2[(size_t)g*N_NODESC + i] : 0;
  int x = v;
  #pragma unroll
  for(int off=1; off<64; off<<=1){ int y = __shfl_up(x, off); if(lane>=off) x += y; }
  if(lane==63) wt[w] = x;
  __syncthreads();
  if(t==0) part2[g*NBLK + b] = wt[0]+wt[1]+wt[2]+wt[3];
}
__global__ void k_scan2(int* __restrict__ part2, int* __restrict__ rp2){
  __shared__ int w0tot;
  int g = blockIdx.x, t = threadIdx.x;   // 128 threads
  int lane = t & 63, w = t >> 6;
  int v = (t < NBLK) ? part2[g*NBLK + t] : 0;
  int x = v;
  #pragma unroll
  for(int off=1; off<64; off<<=1){ int y = __shfl_up(x, off); if(lane>=off) x += y; }
  if(w==0 && lane==63) w0tot = x;
  __syncthreads();
  int incl = x + (w ? w0tot : 0);
  int excl = incl - v;
  if(t < NBLK) part2[g*NBLK + t] = excl;
  if(t == 127) rp2[(size_t)g*NN1 + N_NODESC] = incl;
}
__global__ void k_scan3(const int* __restrict__ cnt2, const int* __restrict__ part2,
                        int* __restrict__ rp2, int* __restrict__ cur2){
  __shared__ int wt[4];
  int g = blockIdx.y, b = blockIdx.x, t = threadIdx.x;
  int lane = t & 63, w = t >> 6;
  int i = b*256 + t;
  int v = (i < N_NODESC) ? cnt2[(size_t)g*N_NODESC + i] : 0;
  int x = v;
  #pragma unroll
  for(int off=1; off<64; off<<=1){ int y = __shfl_up(x, off); if(lane>=off) x += y; }
  if(lane==63) wt[w] = x;
  __syncthreads();
  int wpre = 0;
  #pragma unroll
  for(int j=0;j<4;j++) if(j<w) wpre += wt[j];
  int excl = x - v + wpre + part2[g*NBLK + b];
  if(i < N_NODESC){ rp2[(size_t)g*NN1 + i] = excl; cur2[(size_t)g*N_NODESC + i] = excl; }
}
__global__ void k_scatter2(const int* __restrict__ coei, const int* __restrict__ reei,
                           const float* __restrict__ coew, const float* __restrict__ reew,
                           const float* __restrict__ dinvA, int* __restrict__ cur2,
                           float2* __restrict__ emeta){
  int g = blockIdx.y;
  const int* ei = g ? reei : coei;
  const float* ew = g ? reew : coew;
  int e = blockIdx.x*256 + threadIdx.x;
  if(e < NEC){
    int s = ei[e], d = ei[NEC+e];
    int pos = atomicAdd(&cur2[(size_t)g*N_NODESC + d], 1);
    float nrm = dinvA[(size_t)g*N_NODESC + s]*ew[e]*dinvA[(size_t)g*N_NODESC + d];
    emeta[(size_t)g*NEC + pos] = make_float2(__int_as_float(s), nrm);
  }
}

// ---------- SpMM with fused token scatter, graph-batched ----------
__global__ __launch_bounds__(256)
void k_spmm2(const u16* __restrict__ hWb, size_t hstride,
             const int* __restrict__ rp2, const float2* __restrict__ emb,
             const float* __restrict__ dinvb,
             const float* __restrict__ bias_co, const float* __restrict__ bias_re,
             u16* __restrict__ houtb, size_t ostride,
             const u32* __restrict__ needarr, const u32* __restrict__ need1,
             const int* __restrict__ tmap, const int* __restrict__ nxt,
             float2* __restrict__ tokfb, size_t tfstride,
             u16* __restrict__ tokall, int phase, int gbase){
  const int g = gbase + blockIdx.y;
  const u16* hW = hWb + (size_t)blockIdx.y*hstride;
  const int* rp = rp2 + (size_t)g*NN1;
  const double* em8 = (const double*)(emb + (size_t)g*NEC);
  const float* dinv2 = dinvb + (size_t)g*N_NODESC;
  const float* bias = (g ? bias_re : bias_co) + phase*HIDC;
  u16* hout = houtb + (size_t)blockIdx.y*ostride;
  const u32* flt = (phase==2) ? needarr : (phase==1 ? need1 + (size_t)g*N_NODESC : nullptr);
  float2* tokf = tokfb + (size_t)blockIdx.y*tfstride;
  u16* tokb = tokall + (size_t)g*TOKM*HIDC;

  int v = blockIdx.x*4 + (threadIdx.x>>6);
  if(v >= N_NODESC) return;
  if(flt && !flt[v]) return;
  int lane = threadIdx.x & 63;
  const u32* H = (const u32*)hW;
  float acc[12];
  #pragma unroll
  for(int q=0;q<12;q++) acc[q]=0.f;
  int e0 = rp[v], e1 = rp[v+1];
  int e = e0;
  for(; e+8<=e1; e+=8){
    int s[8]; float w[8];
    #pragma unroll
    for(int j=0;j<8;j++) em_dec(__builtin_nontemporal_load(em8+e+j), s[j], w[j]);
    const u32* r[8];
    #pragma unroll
    for(int j=0;j<8;j++) r[j] = H + (size_t)s[j]*384 + lane;
    u32 u[8][6];
    #pragma unroll
    for(int j=0;j<8;j++){
      #pragma unroll
      for(int q=0;q<6;q++) u[j][q] = r[j][q*64];
    }
    #pragma unroll
    for(int q=0;q<6;q++){
      acc[2*q]   += w[0]*bl(u[0][q]) + w[1]*bl(u[1][q]) + w[2]*bl(u[2][q]) + w[3]*bl(u[3][q]);
      acc[2*q+1] += w[0]*bh(u[0][q]) + w[1]*bh(u[1][q]) + w[2]*bh(u[2][q]) + w[3]*bh(u[3][q]);
      acc[2*q]   += w[4]*bl(u[4][q]) + w[5]*bl(u[5][q]) + w[6]*bl(u[6][q]) + w[7]*bl(u[7][q]);
      acc[2*q+1] += w[4]*bh(u[4][q]) + w[5]*bh(u[5][q]) + w[6]*bh(u[6][q]) + w[7]*bh(u[7][q]);
    }
  }
  for(; e+4<=e1; e+=4){
    int s0,s1,s2,s3; float w0,w1,w2,w3;
    em_dec(__builtin_nontemporal_load(em8+e  ), s0, w0);
    em_dec(__builtin_nontemporal_load(em8+e+1), s1, w1);
    em_dec(__builtin_nontemporal_load(em8+e+2), s2, w2);
    em_dec(__builtin_nontemporal_load(em8+e+3), s3, w3);
    const u32* r0 = H + (size_t)s0*384 + lane;
    const u32* r1 = H + (size_t)s1*384 + lane;
    const u32* r2 = H + (size_t)s2*384 + lane;
    const u32* r3 = H + (size_t)s3*384 + lane;
    u32 u0[6],u1[6],u2[6],u3[6];
    #pragma unroll
    for(int q=0;q<6;q++){ u0[q]=r0[q*64]; u1[q]=r1[q*64]; u2[q]=r2[q*64]; u3[q]=r3[q*64]; }
    #pragma unroll
    for(int q=0;q<6;q++){
      acc[2*q]   += w0*bl(u0[q]) + w1*bl(u1[q]) + w2*bl(u2[q]) + w3*bl(u3[q]);
      acc[2*q+1] += w0*bh(u0[q]) + w1*bh(u1[q]) + w2*bh(u2[q]) + w3*bh(u3[q]);
    }
  }
  for(; e<e1; ++e){
    int ss; float ww;
    em_dec(__builtin_nontemporal_load(em8+e), ss, ww);
    const u32* r = H + (size_t)ss*384 + lane;
    #pragma unroll
    for(int q=0;q<6;q++){ u32 u = r[q*64]; acc[2*q] += ww*bl(u); acc[2*q+1] += ww*bh(u); }
  }
  { float wgt = dinv2[v];
    const u32* r = H + (size_t)v*384 + lane;
    #pragma unroll
    for(int q=0;q<6;q++){ u32 u = r[q*64]; acc[2*q] += wgt*bl(u); acc[2*q+1] += wgt*bh(u); }
  }
  const float2* B2 = (const float2*)bias;
  u32 wv[6];
  #pragma unroll
  for(int q=0;q<6;q++){
    float2 bb = B2[lane + 64*q];
    float x0 = fmaxf(acc[2*q]+bb.x, 0.f);
    float x1 = fmaxf(acc[2*q+1]+bb.y, 0.f);
    wv[q] = pack2(x0, x1);
  }
  if(phase != 2){
    u32* O = (u32*)hout + (size_t)v*384 + lane;
    #pragma unroll
    for(int q=0;q<6;q++) O[q*64] = wv[q];
  }
  int p = tmap[v];                       // wave-uniform; almost always -1
  while(p >= 0){
    float2* TF = tokf + (size_t)p*384 + lane;
    if(phase == 0){
      #pragma unroll
      for(int q=0;q<6;q++)
        TF[q*64] = make_float2(bl(wv[q])*(1.f/3.f), bh(wv[q])*(1.f/3.f));
    } else if(phase == 1){
      #pragma unroll
      for(int q=0;q<6;q++){
        float2 c = TF[q*64];
        c.x += bl(wv[q])*(1.f/3.f); c.y += bh(wv[q])*(1.f/3.f);
        TF[q*64] = c;
      }
    } else {
      u32* TB = (u32*)tokb + (size_t)p*384 + lane;
      #pragma unroll
      for(int q=0;q<6;q++){
        float2 c = TF[q*64];
        c.x += bl(wv[q])*(1.f/3.f); c.y += bh(wv[q])*(1.f/3.f);
        TB[q*64] = pack2(c.x, c.y);
      }
    }
    p = nxt[p];
  }
}

__global__ void k_gather_pn(const float* __restrict__ GT, const int* __restrict__ cids, u16* __restrict__ tokb){
  int d = blockIdx.x*256 + threadIdx.x;
  if(d >= TOKM*384) return;
  int p = d/384, q = d - p*384;
  int cid = cids[p];
  float lo = GT[(size_t)(2*q)*128 + cid];
  float hi = GT[(size_t)(2*q+1)*128 + cid];
  ((u32*)tokb)[d] = pack2(lo, hi);
}

// ---------- XCD-chunked bijective block split (shared) ----------
__device__ __forceinline__ void g_split(int ntM, int ntN, int& bm, int& bn){
  int nwg = ntM*ntN;                       // must be %8==0
  int bid = (int)blockIdx.x;
  int wg = (bid & 7)*(nwg>>3) + (bid>>3);  // XCD-chunked, bijective
  if(ntN <= ntM){ bm = wg/ntN; bn = wg - bm*ntN; }
  else          { bn = wg/ntM; bm = wg - bn*ntM; }
}

// ================= 128x256 single-buffered GEMM (2 blocks/CU) — zero-conv =================
// LDS mainloop: A 128r x 64c bf16 (16KB) @0 ; B 256r x 64c bf16 (32KB) @16384.
// Same row-swizzle as g4/g8: byte ^= ((row&7)<<4), staged via pre-swizzled source.
// 8 waves = 2 wr x 4 wc, wave tile 64x64, acc[4][4]. Simple 2-barrier loop; the
// 2-blocks/CU overlap hides stage/epilogue serialization (m97-style structure).
// Epilogue: 64-row fp32 LDS staging (64KB) -> full-line f32x4 stores; s==0 zero
// column fused. K-accumulation order identical to prior g8 zc -> bit-identical.
template<int NCH>
__device__ __forceinline__ void z_stage(const u16* __restrict__ src, int ldk, int g0, int kt,
                                        char* base, int tid){
  const int c = tid & 7;
  const int r = (tid >> 3) & 63;
  const int csw = (c ^ (r & 7)) << 3;     // pre-swizzled source col (elements)
  #pragma unroll
  for(int h=0; h<NCH; ++h)
    async16(src + (size_t)(g0 + h*64 + r)*ldk + (kt + csw), base + h*8192 + (size_t)tid*16);
}

__global__ __launch_bounds__(512,4)
void gemm_zc2(const u16* __restrict__ TOKALL, const u16* __restrict__ ZWALL,
              const float* __restrict__ zb, const float* __restrict__ zbp,
              const float* __restrict__ invm, float* __restrict__ out){
  extern __shared__ char LDS[];
  const int set = blockIdx.z;
  const u16* A  = TOKALL + (size_t)set*TOKM*HIDC;
  const u16* Bt = ZWALL + (set==2 ? (size_t)ZNC*HIDC : 0);
  const float* bias = (set==2) ? zbp : zb;
  const bool use_mask = (set != 2);
  float* o = out + (size_t)set*OUT_SET;

  const int tid = threadIdx.x;
  const int lane = tid & 63;
  const int wid = tid >> 6;
  const int wr = wid >> 2, wc = wid & 3;
  int bm, bn;
  g_split(TOKM>>7, ZNC>>8, bm, bn);     // 16 x 36
  const int m0 = bm << 7, n0 = bn << 8;

  char* LA = LDS;
  char* LB = LDS + 16384;

  f32x4 acc[4][4];
  f32x4 zv = {0.f,0.f,0.f,0.f};
  #pragma unroll
  for(int m=0;m<4;m++){
    #pragma unroll
    for(int n=0;n<4;n++) acc[m][n] = zv;
  }

  const int NK = HIDC >> 6;   // 12
  for(int T=0; T<NK; ++T){
    __syncthreads();                       // prev frag reads done -> safe overwrite
    z_stage<2>(A,  HIDC, m0, T<<6, LA, tid);
    z_stage<4>(Bt, HIDC, n0, T<<6, LB, tid);
    __syncthreads();                       // vmcnt(0)+barrier: tile visible
    const char* Ab = LA + (wr<<13);
    const char* Bb = LB + (wc<<13);
    short8 bf[4][2];
    #pragma unroll
    for(int n=0;n<4;n++){
      #pragma unroll
      for(int kk=0;kk<2;kk++){
        int row = (n<<4) + (lane&15);
        int cb = ((kk<<6) + ((lane>>4)<<4)) ^ ((lane&7)<<4);
        bf[n][kk] = *(const short8*)(Bb + row*128 + cb);
      }
    }
    #pragma unroll
    for(int m=0;m<4;m++){
      short8 af[2];
      #pragma unroll
      for(int kk=0;kk<2;kk++){
        int row = (m<<4) + (lane&15);
        int cb = ((kk<<6) + ((lane>>4)<<4)) ^ ((lane&7)<<4);
        af[kk] = *(const short8*)(Ab + row*128 + cb);
      }
      #pragma unroll
      for(int n=0;n<4;n++){
        #pragma unroll
        for(int kk=0;kk<2;kk++) mfma16(acc[m][n], af[kk], bf[n][kk]);
      }
    }
  }

  const int l = n0 / HIDC;                 // 256-span never straddles a layer
  const int oc0 = n0 - l*HIDC;
  const int lo = lane & 15, hi = lane >> 4;

  #pragma unroll
  for(int pass=0; pass<2; ++pass){
    __syncthreads();
    if(wr == pass){
      #pragma unroll
      for(int m=0;m<4;m++){
        #pragma unroll
        for(int n=0;n<4;n++){
          int col = (wc<<6) + (n<<4) + lo;      // 0..255
          float badd = bias[n0 + col];
          #pragma unroll
          for(int r=0;r<4;r++){
            int lr = (m<<4) + (hi<<2) + r;      // 0..63
            *(float*)(LDS + (size_t)lr*1024 + ((col<<2) ^ ((lr&7)<<4))) = acc[m][n][r] + badd;
          }
        }
      }
    }
    __syncthreads();
    // 64 rows x 1024B ; wave wid stores rows wid, wid+8, ...
    #pragma unroll
    for(int i=0;i<8;i++){
      int lr = (i<<3) + wid;
      int rr = m0 + (pass<<6) + lr;             // global token row
      int b = rr >> 9, s = rr & 511;
      f32x4 v = *(const f32x4*)(LDS + (size_t)lr*1024 + ((lane<<4) ^ ((lr&7)<<4)));
      if(use_mask){ float w = invm[rr]; v = v * w; }
      *(f32x4*)(o + (size_t)((l*4+b)*513 + (s+1))*HIDC + oc0 + (lane<<2)) = v;
      if(s == 0){
        f32x4 z4 = {0.f,0.f,0.f,0.f};
        *(f32x4*)(o + (size_t)((l*4+b)*513)*HIDC + oc0 + (lane<<2)) = z4;
      }
    }
  }
}

// ================= 128x128 2-phase GEMM core (2 blocks/CU) — used for GCN/CBT =================
#define G4_ABUF(b) ((b)*32768)
#define G4_BBUF(b) ((b)*32768 + 16384)

__device__ __forceinline__ void g4_stage(const u16* __restrict__ src, int ldk, int g0, int kt,
                                         char* base, int tid){
  const int lane = tid & 63;
  const int csw = ((lane&7) ^ (lane>>3)) << 3;   // pre-swizzled source col (elements)
  const int r = tid >> 3;                        // 0..31
  #pragma unroll
  for(int h=0; h<4; ++h)
    async16(src + (size_t)(g0 + h*32 + r)*ldk + (kt + csw), base + h*4096 + (size_t)tid*16);
}

__device__ __forceinline__ void g4_core(const u16* __restrict__ A, const u16* __restrict__ Bt,
                                        int K, int m0, int n0,
                                        f32x4 (&acc)[4][4], char* LDS, int tid){
  const int lane = tid & 63;
  const int wid = tid >> 6;
  const int wr = wid >> 1, wc = wid & 1;
  const int NK = K >> 6;   // requires NK>=2

  g4_stage(A,  K, m0,  0, LDS + G4_ABUF(0), tid);
  g4_stage(Bt, K, n0,  0, LDS + G4_BBUF(0), tid);
  g4_stage(A,  K, m0, 64, LDS + G4_ABUF(1), tid);
  g4_stage(Bt, K, n0, 64, LDS + G4_BBUF(1), tid);

  short8 af[4][2], bf[4][2];
  for(int T=0; T<NK; ++T){
    const int buf = T & 1;
    const char* Ab = LDS + G4_ABUF(buf) + wr*8192;
    const char* Bb = LDS + G4_BBUF(buf) + wc*8192;
    if(T+1 < NK) asm volatile("s_waitcnt vmcnt(8)" ::: "memory");
    else         asm volatile("s_waitcnt vmcnt(0)" ::: "memory");
    __builtin_amdgcn_sched_barrier(0);
    __builtin_amdgcn_s_barrier();
    __builtin_amdgcn_sched_barrier(0);
    #pragma unroll
    for(int m=0;m<4;m++){
      #pragma unroll
      for(int kk=0;kk<2;kk++){
        int row = (m<<4) + (lane&15);
        int cb = ((kk<<6) + ((lane>>4)<<4)) ^ ((lane&7)<<4);
        af[m][kk] = *(const short8*)(Ab + row*128 + cb);
        bf[m][kk] = *(const short8*)(Bb + row*128 + cb);
      }
    }
    asm volatile("s_waitcnt lgkmcnt(0)" ::: "memory");
    __builtin_amdgcn_sched_barrier(0);
    __builtin_amdgcn_s_setprio(1);
    #pragma unroll
    for(int m=0;m<2;m++){
      #pragma unroll
      for(int n=0;n<4;n++){
        #pragma unroll
        for(int kk=0;kk<2;kk++) mfma16(acc[m][n], af[m][kk], bf[n][kk]);
      }
    }
    __builtin_amdgcn_s_setprio(0);
    __builtin_amdgcn_sched_barrier(0);
    __builtin_amdgcn_s_barrier();     // all waves' ds_reads done -> buf free
    __builtin_amdgcn_sched_barrier(0);
    if(T+2 < NK){
      g4_stage(A,  K, m0, (T+2)<<6, LDS + G4_ABUF(buf), tid);
      g4_stage(Bt, K, n0, (T+2)<<6, LDS + G4_BBUF(buf), tid);
    }
    __builtin_amdgcn_s_setprio(1);
    #pragma unroll
    for(int m=2;m<4;m++){
      #pragma unroll
      for(int n=0;n<4;n++){
        #pragma unroll
        for(int kk=0;kk<2;kk++) mfma16(acc[m][n], af[m][kk], bf[n][kk]);
      }
    }
    __builtin_amdgcn_s_setprio(0);
    __builtin_amdgcn_sched_barrier(0);
  }
}

// bias + bf16 out, used for cbT (pn path)
__global__ __launch_bounds__(256,2)
void gemm4p_bias(const u16* __restrict__ A, const u16* __restrict__ Bt,
                 int M, int N, int K,
                 u16* __restrict__ outB, const float* __restrict__ bias){
  extern __shared__ char LDS[];
  const int tid = threadIdx.x;
  const int lane = tid & 63;
  const int wid = tid >> 6;
  const int wr = wid >> 1, wc = wid & 1;
  int bm, bn;
  g_split(M>>7, N>>7, bm, bn);
  const int m0 = bm << 7, n0 = bn << 7;

  f32x4 acc[4][4];
  f32x4 zv = {0.f,0.f,0.f,0.f};
  #pragma unroll
  for(int m=0;m<4;m++){
    #pragma unroll
    for(int n=0;n<4;n++) acc[m][n] = zv;
  }
  g4_core(A, Bt, K, m0, n0, acc, LDS, tid);

  const int rbase = (lane>>4)<<2;
  const int cbase = lane & 15;
  #pragma unroll
  for(int m=0;m<4;m++){
    int row0 = m0 + (wr<<6) + (m<<4) + rbase;
    #pragma unroll
    for(int n=0;n<4;n++){
      int col = n0 + (wc<<6) + (n<<4) + cbase;
      #pragma unroll
      for(int r=0;r<4;r++){
        float v = acc[m][n][r] + bias[row0+r];
        outB[(size_t)(row0+r)*N + col] = (u16)f2b1(v);
      }
    }
  }
}

// GCN layer GEMM, graph-batched via blockIdx.z (z stride 0 in sequential fallback)
__global__ __launch_bounds__(256,2)
void gemm4p_gcn(const u16* __restrict__ Xb, size_t xstride,
                const u16* __restrict__ wt2, int layer,
                u16* __restrict__ outb, size_t ostride, int gbase){
  extern __shared__ char LDS[];
  const int g = gbase + blockIdx.z;
  const u16* A = Xb + (size_t)blockIdx.z*xstride;
  const u16* Bt = wt2 + ((size_t)g*3 + layer)*HIDC*HIDC;
  u16* outB = outb + (size_t)blockIdx.z*ostride;

  const int tid = threadIdx.x;
  const int lane = tid & 63;
  const int wid = tid >> 6;
  const int wr = wid >> 1, wc = wid & 1;
  int bm, bn;
  g_split(M_PAD>>7, HIDC>>7, bm, bn);      // 240 x 6
  const int m0 = bm << 7, n0 = bn << 7;

  f32x4 acc[4][4];
  f32x4 zv = {0.f,0.f,0.f,0.f};
  #pragma unroll
  for(int m=0;m<4;m++){
    #pragma unroll
    for(int n=0;n<4;n++) acc[m][n] = zv;
  }
  g4_core(A, Bt, HIDC, m0, n0, acc, LDS, tid);

  const int rbase = (lane>>4)<<2;
  const int cbase = lane & 15;
  #pragma unroll
  for(int m=0;m<4;m++){
    int row0 = m0 + (wr<<6) + (m<<4) + rbase;
    #pragma unroll
    for(int n=0;n<4;n++){
      int col = n0 + (wc<<6) + (n<<4) + cbase;
      #pragma unroll
      for(int r=0;r<4;r++)
        outB[(size_t)(row0+r)*HIDC + col] = (u16)f2b1(acc[m][n][r]);
    }
  }
}

// ---------- split-K GEMM (m97-style): atomics into GT ----------
__global__ __launch_bounds__(256,2)
void gemm_splitk(const u16* __restrict__ A, const u16* __restrict__ Bt,
                 int M, int N, int K, float* __restrict__ outF, int kchunk){
  __shared__ u16 As[128*64];
  __shared__ u16 Bs[128*64];
  const int t = threadIdx.x;
  const int lane = t & 63;
  const int w = t >> 6;
  const int wr = w >> 1, wc = w & 1;
  int nchunks = (K + kchunk - 1)/kchunk;
  int bm = (int)blockIdx.x / nchunks;
  int ch = (int)blockIdx.x - bm*nchunks;
  int k0 = ch*kchunk, k1 = k0 + kchunk; if(k1 > K) k1 = K;
  const int m0 = bm << 7, n0 = 0;

  f32x4 zv = {0.f,0.f,0.f,0.f};
  f32x4 acc[4][4];
  #pragma unroll
  for(int m=0;m<4;m++){
    #pragma unroll
    for(int n=0;n<4;n++) acc[m][n] = zv;
  }
  const int srow = t >> 3;
  const int scol = (t & 7) << 3;
  const u16* Ag = A + (size_t)(m0 + srow)*K + scol;
  const u16* Bg = Bt + (size_t)(n0 + srow)*K + scol;
  u16* Al = &As[t*8];
  u16* Bl = &Bs[t*8];

  for(int kt=k0; kt<k1; kt+=64){
    __syncthreads();
    #pragma unroll
    for(int i=0;i<4;i++){
      async16(Ag + (size_t)(i*32)*K + kt, Al + i*2048);
      async16(Bg + (size_t)(i*32)*K + kt, Bl + i*2048);
    }
    __syncthreads();
    #pragma unroll
    for(int kk=0; kk<64; kk+=32){
      const int ko = kk + ((lane>>4)<<3);
      short8 af[4], bfv[4];
      #pragma unroll
      for(int m=0;m<4;m++) af[m] = *(const short8*)&As[((wr<<6)+(m<<4)+(lane&15))*64 + ko];
      #pragma unroll
      for(int n=0;n<4;n++) bfv[n] = *(const short8*)&Bs[((wc<<6)+(n<<4)+(lane&15))*64 + ko];
      #pragma unroll
      for(int m=0;m<4;m++){
        #pragma unroll
        for(int n=0;n<4;n++) mfma16(acc[m][n], af[m], bfv[n]);
      }
    }
  }
  const int rbase = (lane>>4)<<2;
  const int cbase = lane & 15;
  #pragma unroll
  for(int m=0;m<4;m++){
    int row0 = m0 + (wr<<6) + (m<<4) + rbase;
    #pragma unroll
    for(int n=0;n<4;n++){
      int col = n0 + (wc<<6) + (n<<4) + cbase;
      #pragma unroll
      for(int r=0;r<4;r++) atomicAdd(&outF[(size_t)(row0+r)*N + col], acc[m][n][r]);
    }
  }
}

// ---------- host ----------
extern "C" void kernel_launch(void* const* d_in, const int* in_sizes, int n_in,
                              void* d_out, int out_size, void* d_ws, size_t ws_size,
                              hipStream_t stream){
  const float* word  = (const float*)d_in[0];
  const int*   ids   = (const int*)d_in[1];
  const int*   cids  = (const int*)d_in[2];
  const void*  mask  = d_in[3];
  const int*   co_ei = (const int*)d_in[4];
  const float* co_ew = (const float*)d_in[5];
  const int*   re_ei = (const int*)d_in[6];
  const float* re_ew = (const float*)d_in[7];
  const float* png   = (const float*)d_in[8];
  const float* co_W  = (const float*)d_in[9];
  const float* co_b  = (const float*)d_in[10];
  const float* re_W  = (const float*)d_in[11];
  const float* re_b  = (const float*)d_in[12];
  const float* pn_W  = (const float*)d_in[13];
  const float* pn_b  = (const float*)d_in[14];
  const float* zw    = (const float*)d_in[15];
  const float* zb    = (const float*)d_in[16];
  const float* zwp   = (const float*)d_in[17];
  const float* zbp   = (const float*)d_in[18];
  float* out = (float*)d_out;

  hipFuncSetAttribute((const void*)gemm4p_bias, hipFuncAttributeMaxDynamicSharedMemorySize, G4_LDS);
  hipFuncSetAttribute((const void*)gemm4p_gcn,  hipFuncAttributeMaxDynamicSharedMemorySize, G4_LDS);
  hipFuncSetAttribute((const void*)gemm_zc2,    hipFuncAttributeMaxDynamicSharedMemorySize, ZC_LDS);

  const size_t MH = (size_t)M_PAD*HIDC;          // elements
  const size_t TFS = (size_t)TOKM*384;           // float2 elements
  // batched mode needs ~313MB of workspace; fall back to sequential otherwise
  const bool batched = ws_size >= ((size_t)340 << 20);

  char* wsb = (char*)d_ws;
  size_t off = 0;
  auto alloc = [&](size_t bytes)->void*{ void* p = wsb + off; off += (bytes + 255) & ~(size_t)255; return p; };
  u16* WORDB = (u16*)alloc(MH*2);
  u16* BUFB  = (u16*)alloc(MH*2*(batched?2:1));
  u16* BUFX  = (u16*)alloc(MH*2*(batched?2:1));
  u16* ZWALL = (u16*)alloc((size_t)2*ZNC*HIDC*2);
  u16* WT2   = (u16*)alloc((size_t)2*3*HIDC*HIDC*2);
  u16* PNWB  = (u16*)alloc((size_t)HIDC*HIDC*2);
  u16* PNB   = (u16*)alloc((size_t)128*M_PAD*2);
  u16* TOKALL= (u16*)alloc((size_t)3*TOKM*HIDC*2);
  float2* TOKF = (float2*)alloc(TFS*8*(batched?2:1));
  // ---- contiguous zero-init group (one memset) ----
  size_t zg0 = off;
  u32*   NEED = (u32*)alloc((size_t)N_NODESC*4);
  u32*   NEED1= (u32*)alloc((size_t)2*N_NODESC*4);
  float* DEG2 = (float*)alloc((size_t)2*N_NODESC*4);
  int*   CNT2 = (int*)alloc((size_t)2*N_NODESC*4);
  float* GT   = (float*)alloc((size_t)HIDC*128*4);
  size_t zg_bytes = off - zg0;
  // ------------------------------------------------
  float* DINVA = (float*)alloc((size_t)2*N_NODESC*4);
  float* DINVB = (float*)alloc((size_t)2*N_NODESC*4);
  int*   RP2  = (int*)alloc((size_t)2*NN1*4);
  int*   CUR2 = (int*)alloc((size_t)2*N_NODESC*4);
  int*   PART2= (int*)alloc((size_t)2*NBLK*4);
  float2* EMETA=(float2*)alloc((size_t)2*NEC*8);
  int*   TMAP = (int*)alloc((size_t)N_NODESC*4);
  int*   NXT  = (int*)alloc((size_t)TOKM*4);
  float* INVM = (float*)alloc((size_t)TOKM*4);
  (void)ws_size; (void)in_sizes; (void)n_in; (void)out_size;

  const int GD_TOK = (TOKM*384 + 255)/256;
  const int GD_E   = (NEC + 255)/256;
  const int SPMM_GD  = (N_NODESC + 3)/4;
  const int PN_NCHUNKS = M_PAD/PN_KCHUNK;               // 60
  const int G_PN  = (HIDC/128)*PN_NCHUNKS;              // 360
  const int G4_GCN = (M_PAD/128)*(HIDC/128);            // 1440
  const int G4_CBT = (HIDC/128)*(M_PAD/128);            // 1440
  const int G_ZC2  = (TOKM/128)*(ZNC/256);              // 576
  const int NCONVALL = HIDC*HIDC/2 + 2*(ZNC*HIDC/2) + 128*(M_PAD/2);

  // ---- prep ----
  hipMemsetAsync(wsb + zg0, 0, zg_bytes, stream);             // NEED,NEED1,DEG2,CNT2,GT
  hipMemsetAsync(TMAP, 0xFF, (size_t)N_NODESC*4, stream);
  hipMemsetAsync(TOKALL, 0, (size_t)2*TOKM*HIDC*2, stream);   // co/re segments (padding tokens stay 0)
  k_invmask<<<1,256,0,stream>>>(mask, INVM);
  k_needed<<<(TOKM+255)/256,256,0,stream>>>(ids, NEED, NEED1, TMAP, NXT);
  k_need_expand<<<dim3(GD_E,2),256,0,stream>>>(co_ei, re_ei, NEED, NEED1);
  k_convAll<<<(NCONVALL + 255)/256,256,0,stream>>>(pn_W, zw, zwp, png, PNWB, ZWALL, PNB);
  k_conv_pad<<<(M_PAD*384 + 255)/256,256,0,stream>>>(word, WORDB, N_NODESC, M_PAD);
  k_transposeW2<<<dim3((3*HIDC*384 + 255)/256, 2),256,0,stream>>>(co_W, re_W, WT2);

  // ---- batched CSR build ----
  k_degcnt2<<<dim3(GD_E,2),256,0,stream>>>(co_ei, re_ei, co_ew, re_ew, DEG2, CNT2);
  k_scan1<<<dim3(NBLK,2),256,0,stream>>>(CNT2, PART2, DEG2, DINVA, DINVB);
  k_scan2<<<2,128,0,stream>>>(PART2, RP2);
  k_scan3<<<dim3(NBLK,2),256,0,stream>>>(CNT2, PART2, RP2, CUR2);
  k_scatter2<<<dim3(GD_E,2),256,0,stream>>>(co_ei, re_ei, co_ew, re_ew, DINVA, CUR2, EMETA);

  // ---- pn path: cbT = pnW·word^T (+row bias), GT = cbT·pn^T (split-K), gather ----
  gemm4p_bias<<<G4_CBT,256,G4_LDS,stream>>>(PNWB, WORDB, HIDC, M_PAD, HIDC, BUFX, pn_b);
  gemm_splitk<<<G_PN,256,0,stream>>>(BUFX, PNB, HIDC, 128, M_PAD, GT, PN_KCHUNK);
  k_gather_pn<<<GD_TOK,256,0,stream>>>(GT, cids, TOKALL + (size_t)2*TOKM*HIDC);

  // ---- GCN stacks (graph-batched when workspace allows) ----
  // layer filters: L0 = none; L1 = NEED1; L2 = NEED. token writes fused in spmm.
  if(batched){
    for(int i=0;i<3;i++){
      gemm4p_gcn<<<dim3(G4_GCN,1,2),256,G4_LDS,stream>>>(
          (i==0)? WORDB : BUFX, (i==0)? 0 : MH, WT2, i, BUFB, MH, 0);
      k_spmm2<<<dim3(SPMM_GD,2),256,0,stream>>>(
          BUFB, MH, RP2, EMETA, DINVB, co_b, re_b, BUFX, MH,
          NEED, NEED1, TMAP, NXT, TOKF, TFS, TOKALL, i, 0);
    }
  } else {
    for(int g=0; g<2; ++g){
      const u16* X = WORDB;
      for(int i=0;i<3;i++){
        gemm4p_gcn<<<dim3(G4_GCN,1,1),256,G4_LDS,stream>>>(X, 0, WT2, i, BUFB, 0, g);
        k_spmm2<<<dim3(SPMM_GD,1),256,0,stream>>>(
            BUFB, 0, RP2, EMETA, DINVB, co_b, re_b, BUFX, 0,
            NEED, NEED1, TMAP, NXT, TOKF, 0, TOKALL, i, g);
        X = BUFX;
      }
    }
  }

  // ---- zero-convs -> outputs (zero column + s==0 fused) ----
  dim3 zgrid(G_ZC2, 1, 3);
  gemm_zc2<<<zgrid,512,ZC_LDS,stream>>>(TOKALL, ZWALL, zb, zbp, INVM, out);
}